// Round 6
// baseline (650.913 us; speedup 1.0000x reference)
//
#include <hip/hip_runtime.h>

// ---------------------------------------------------------------------------
// RefinedQuantumEntanglementLayer on MI355X (gfx950)
//
// out = (l2norm(x) @ expm(Mr-Mr^T) @ expm(Mi-Mi^T) + bias)^2 * softmax(qg)
//
// r6: the whole expm chain (skew, powers, Paterson-Stockmeyer deg-8, 3
// squarings, W) runs in ONE persistent 512-block kernel with an atomic
// grid barrier between phases -- r5 spent ~90us on dispatch overhead/ramp
// for 11 tiny dependent kernels. 512 blocks at 2/CU (32KB LDS, ~104 VGPR,
// __launch_bounds__(256,2)) are co-resident by construction.
//
// Degree-8 PS (was 12): ||X||~1.13 at s=3 -> truncation ~2e-4 in U after
// squarings, negligible vs measured bf16 noise (41x margin at deg-12).
//   X2 = -f(X,X); X3 = -f(X2,X); X4 = f(X2,X2)        [f(A,B) = A*B^T]
//   q0 = I+X+X2/2+X3/6 (f32); q1t = (q1)^T elementwise (odd sign flips)
//   E  = f(X4,q1t)+q0 [dual-write -> Et]
//   squarings E' = f(E,Et) [dual -> E't]; W = U^T = f(E3t_B, E3_A)
// main: out = f(Xn,W), epilogue (.+bias)^2*gate (unchanged r5 256^2 kernel).
// ---------------------------------------------------------------------------

typedef unsigned int u32;
typedef unsigned short u16;
typedef __attribute__((ext_vector_type(8))) short short8;   // 8 x bf16 raw
typedef __attribute__((ext_vector_type(4))) float f32x4;

#define GLOBAL_AS __attribute__((address_space(1)))
#define LDS_AS    __attribute__((address_space(3)))

constexpr int D = 1024;
constexpr float EXPM_SCALE = 1.0f / 8.0f;   // s = 3 squarings

__device__ __forceinline__ u16 f2bf(float f) {
  union { float f; u32 u; } v; v.f = f;
  u32 r = (v.u + 0x7FFFu + ((v.u >> 16) & 1u)) >> 16;
  return (u16)r;
}
__device__ __forceinline__ float bf2f(u16 u) {
  union { u32 u; float f; } v; v.u = ((u32)u) << 16;
  return v.f;
}

// async global->LDS, 16B per lane; lds base must be wave-uniform.
__device__ __forceinline__ void g2l16(const void* g, void* l) {
  __builtin_amdgcn_global_load_lds((const GLOBAL_AS u32*)g, (LDS_AS u32*)l,
                                   16, 0, 0);
}

// ---------------------------------------------------------------------------
// normalize rows of x -> bf16
__global__ __launch_bounds__(256) void normalize_kernel(
    const float* __restrict__ x, u16* __restrict__ Xn) {
  const int r = blockIdx.x;
  const int t = threadIdx.x;
  const float4 v = ((const float4*)(x + (size_t)r * D))[t];
  float ss = v.x * v.x + v.y * v.y + v.z * v.z + v.w * v.w;
  for (int o = 32; o; o >>= 1) ss += __shfl_down(ss, o);
  __shared__ float s4[4];
  if ((t & 63) == 0) s4[t >> 6] = ss;
  __syncthreads();
  const float tot = s4[0] + s4[1] + s4[2] + s4[3];
  const float inv = rsqrtf(fmaxf(tot, 1e-12f));
  ushort4 o4;
  o4.x = f2bf(v.x * inv); o4.y = f2bf(v.y * inv);
  o4.z = f2bf(v.z * inv); o4.w = f2bf(v.w * inv);
  ((ushort4*)(Xn + (size_t)r * D))[t] = o4;
}

// ---------------------------------------------------------------------------
// fused chain kernel
struct CJob {
  const u16 *A, *B;
  const float* C;
  u16 *Dst, *DT;
  float alpha;
};
struct ChainParams {
  const float *Mr, *Mi, *qg;
  float* gate_out;
  u16 *X0, *X1;
  const u16 *bqX[2], *bqX2[2], *bqX3[2], *bqX4[2];
  float* bq_q0[2];
  u16* bq_q1t[2];
  CJob rounds[7][4];
  int nunits[7];
  u32 *bar_cnt, *bar_gen;
};

// grid barrier: arrive-and-spin on generation, agent-scope atomics.
// Spin capped (~0.5s) so a logic failure is loud (absmax fail), not a hang.
__device__ __forceinline__ void gsync(u32* cnt, u32* gen, u32 nb) {
  __syncthreads();
  if (threadIdx.x == 0) {
    __threadfence();  // publish this block's writes device-wide
    const u32 g =
        __hip_atomic_load(gen, __ATOMIC_RELAXED, __HIP_MEMORY_SCOPE_AGENT);
    const u32 a = __hip_atomic_fetch_add(cnt, 1u, __ATOMIC_ACQ_REL,
                                         __HIP_MEMORY_SCOPE_AGENT);
    if (a == nb - 1u) {
      __hip_atomic_store(cnt, 0u, __ATOMIC_RELAXED, __HIP_MEMORY_SCOPE_AGENT);
      __hip_atomic_store(gen, g + 1u, __ATOMIC_RELEASE,
                         __HIP_MEMORY_SCOPE_AGENT);
    } else {
      for (u32 it = 0; it < 1200000u; ++it) {
        if (__hip_atomic_load(gen, __ATOMIC_ACQUIRE,
                              __HIP_MEMORY_SCOPE_AGENT) != g)
          break;
        __builtin_amdgcn_s_sleep(16);
      }
    }
    __threadfence();  // acquire side: invalidate stale cache
  }
  __syncthreads();
}

// X = (M - M^T) * EXPM_SCALE -> bf16 (one 64x64 tile)
__device__ void skew_tile(const float* M, u16* X, int bi, int bj, int tid,
                          char* smem) {
  float(*t2)[67] = (float(*)[67])smem;
  const int r0 = tid >> 4, c0 = (tid & 15) * 4;
  float4 own[4];
#pragma unroll
  for (int i = 0; i < 4; ++i) {
    const int r = i * 16 + r0;
    own[i] = *(const float4*)(M + (size_t)(bi * 64 + r) * D + bj * 64 + c0);
    const float4 tr =
        *(const float4*)(M + (size_t)(bj * 64 + r) * D + bi * 64 + c0);
    t2[r][c0 + 0] = tr.x; t2[r][c0 + 1] = tr.y;
    t2[r][c0 + 2] = tr.z; t2[r][c0 + 3] = tr.w;
  }
  __syncthreads();
#pragma unroll
  for (int i = 0; i < 4; ++i) {
    const int r = i * 16 + r0;
    const float o[4] = {own[i].x, own[i].y, own[i].z, own[i].w};
    ushort4 hv;
    u16* hp = (u16*)&hv;
#pragma unroll
    for (int j = 0; j < 4; ++j)
      hp[j] = f2bf((o[j] - t2[c0 + j][r]) * EXPM_SCALE);
    *(ushort4*)(X + (size_t)(bi * 64 + r) * D + bj * 64 + c0) = hv;
  }
}

// one 64x64 GEMM tile: Dst = alpha*(A*B^T) [+C], optional dual write DT.
// r3-proven body: BK=64, 4 waves (2x2, 32x32), dbuf 1-ahead prefetch.
__device__ void gemm_tile(const CJob jb, int bi, int bj, int tid, u16* ldsA,
                          u16* ldsB) {
  const int w = tid >> 6, lane = tid & 63;
  const int wr = w >> 1, wc = w & 1;
  f32x4 acc[2][2];
#pragma unroll
  for (int m = 0; m < 2; ++m)
#pragma unroll
    for (int n = 0; n < 2; ++n) acc[m][n] = f32x4{0.f, 0.f, 0.f, 0.f};
  const int r_l = lane >> 3, c_l = lane & 7;

  auto stage = [&](int buf, int kt) {
    const int k0 = kt * 64;
#pragma unroll
    for (int p = 0; p < 2; ++p) {
      const int row = p * 32 + w * 8 + r_l;
      const int chunk = c_l ^ (row & 7);  // inverse swizzle on global source
      g2l16(jb.A + (size_t)(bi * 64 + row) * D + k0 + chunk * 8,
            (char*)ldsA + buf * 8192 + p * 4096 + w * 1024);
      g2l16(jb.B + (size_t)(bj * 64 + row) * D + k0 + chunk * 8,
            (char*)ldsB + buf * 8192 + p * 4096 + w * 1024);
    }
  };

  stage(0, 0);
  __syncthreads();
  int buf = 0;
  for (int kt = 0; kt < 16; ++kt) {
    if (kt < 15) stage(buf ^ 1, kt + 1);  // prefetch flies under MFMAs
#pragma unroll
    for (int h = 0; h < 2; ++h) {
      const int kk = h * 32 + (lane >> 4) * 8;
      short8 a[2], b[2];
#pragma unroll
      for (int m = 0; m < 2; ++m) {
        const int row = wr * 32 + m * 16 + (lane & 15);
        const int off = row * 128 + ((kk * 2) ^ ((row & 7) << 4));
        a[m] = *(const short8*)((const char*)ldsA + buf * 8192 + off);
      }
#pragma unroll
      for (int n = 0; n < 2; ++n) {
        const int row = wc * 32 + n * 16 + (lane & 15);
        const int off = row * 128 + ((kk * 2) ^ ((row & 7) << 4));
        b[n] = *(const short8*)((const char*)ldsB + buf * 8192 + off);
      }
#pragma unroll
      for (int m = 0; m < 2; ++m)
#pragma unroll
        for (int n = 0; n < 2; ++n)
          acc[m][n] = __builtin_amdgcn_mfma_f32_16x16x32_bf16(
              a[m], b[n], acc[m][n], 0, 0, 0);
    }
    __syncthreads();
    buf ^= 1;
  }
  const int or0 = bi * 64 + wr * 32, oc0 = bj * 64 + wc * 32;
#pragma unroll
  for (int m = 0; m < 2; ++m)
#pragma unroll
    for (int n = 0; n < 2; ++n) {
      const int row0 = or0 + m * 16 + (lane >> 4) * 4;
      const int col = oc0 + n * 16 + (lane & 15);
      ushort4 dv;
      u16* dp = (u16*)&dv;
#pragma unroll
      for (int r = 0; r < 4; ++r) {
        float v = acc[m][n][r] * jb.alpha;
        if (jb.C) v += jb.C[(size_t)(row0 + r) * D + col];
        dp[r] = f2bf(v);
        jb.Dst[(size_t)(row0 + r) * D + col] = dp[r];
      }
      if (jb.DT)  // transposed tile: DT[col][row0..row0+3], one 8B store
        *(ushort4*)(jb.DT + (size_t)col * D + row0) = dv;
    }
}

// elementwise: q0 = I+X+X2/2+X3/6 (f32); q1t = I/24 - X/120 + X2/720
//              - X3/5040 + X4/40320 (bf16)   [8 elems/thread/matrix]
__device__ void buildq_body(const ChainParams& p, int bid, int tid) {
  const int gtid = bid * 256 + tid;
  const size_t idx0 = (size_t)gtid * 8;
  const int i = (int)(idx0 >> 10), j0 = (int)(idx0 & 1023);
#pragma unroll
  for (int m = 0; m < 2; ++m) {
    const short8 xv = *(const short8*)(p.bqX[m] + idx0);
    const short8 x2v = *(const short8*)(p.bqX2[m] + idx0);
    const short8 x3v = *(const short8*)(p.bqX3[m] + idx0);
    const short8 x4v = *(const short8*)(p.bqX4[m] + idx0);
    float q0o[8];
    short8 q1o;
#pragma unroll
    for (int k = 0; k < 8; ++k) {
      const float d = (i == (j0 + k)) ? 1.f : 0.f;
      const float x = bf2f((u16)xv[k]);
      const float x2 = bf2f((u16)x2v[k]);
      const float x3 = bf2f((u16)x3v[k]);
      const float x4 = bf2f((u16)x4v[k]);
      q0o[k] = d + x + x2 * 0.5f + x3 * (1.f / 6.f);
      q1o[k] = (short)f2bf(d * (1.f / 24.f) - x * (1.f / 120.f) +
                           x2 * (1.f / 720.f) - x3 * (1.f / 5040.f) +
                           x4 * (1.f / 40320.f));
    }
#pragma unroll
    for (int k = 0; k < 8; ++k) p.bq_q0[m][idx0 + k] = q0o[k];
    *(short8*)(p.bq_q1t[m] + idx0) = q1o;
  }
}

// softmax of qg (block 0 only, 256 threads x 4 elems)
__device__ void gate_body(const float* qg, float* gout, int tid, char* smem) {
  float* red = (float*)smem;
  const float4 v = ((const float4*)qg)[tid];
  float mx = fmaxf(fmaxf(v.x, v.y), fmaxf(v.z, v.w));
#pragma unroll
  for (int o = 32; o; o >>= 1) mx = fmaxf(mx, __shfl_xor(mx, o));
  if ((tid & 63) == 0) red[tid >> 6] = mx;
  __syncthreads();
  const float M = fmaxf(fmaxf(red[0], red[1]), fmaxf(red[2], red[3]));
  __syncthreads();
  const float e0 = __expf(v.x - M), e1 = __expf(v.y - M),
              e2 = __expf(v.z - M), e3 = __expf(v.w - M);
  float s = e0 + e1 + e2 + e3;
#pragma unroll
  for (int o = 32; o; o >>= 1) s += __shfl_xor(s, o);
  if ((tid & 63) == 0) red[tid >> 6] = s;
  __syncthreads();
  const float S = red[0] + red[1] + red[2] + red[3];
  const float4 o4 = {e0 / S, e1 / S, e2 / S, e3 / S};
  ((float4*)gout)[tid] = o4;
}

__global__ __launch_bounds__(256, 2) void chain_fused(ChainParams p) {
  __shared__ __align__(16) char smem[32768];
  u16* ldsA = (u16*)smem;            // [2][4096] u16
  u16* ldsB = (u16*)(smem + 16384);  // [2][4096] u16
  const int bid = blockIdx.x, tid = threadIdx.x;
  const u32 nb = gridDim.x;

  // P0: skew (512 jobs: mat x 16 x 16)
  {
    const int z = bid >> 8, t = bid & 255;
    skew_tile(z ? p.Mi : p.Mr, z ? p.X1 : p.X0, t >> 4, t & 15, tid, smem);
  }
  gsync(p.bar_cnt, p.bar_gen, nb);

  // 7 GEMM rounds; buildq(+gate) interleaved after round 1
  for (int r = 0; r < 7; ++r) {
    const int njobs = p.nunits[r] << 8;
    for (int j = bid; j < njobs; j += 512) {
      gemm_tile(p.rounds[r][j >> 8], (j >> 4) & 15, j & 15, tid, ldsA, ldsB);
    }
    if (r < 6) gsync(p.bar_cnt, p.bar_gen, nb);
    if (r == 1) {
      buildq_body(p, bid, tid);
      if (bid == 0) gate_body(p.qg, p.gate_out, tid, smem);
      gsync(p.bar_cnt, p.bar_gen, nb);
    }
  }
}

// ---------------------------------------------------------------------------
// main GEMM (r5, unchanged): out[r][c] = (f(Xn,W) + bias[c])^2 * gate[c]
// 256x256 tile, BK=64, 8 waves (2x4), 128 KiB dbuf LDS, 1-ahead prefetch.
__global__ __launch_bounds__(512, 1) void main_gemm_kernel(
    const u16* __restrict__ Xn, const u16* __restrict__ Wm,
    const float* __restrict__ bias, const float* __restrict__ gate,
    float* __restrict__ out) {
  const int tid = threadIdx.x;
  const int wid = tid >> 6, lane = tid & 63;
  const int wr = wid >> 2, wc = wid & 3;   // 2 x 4 waves
  __shared__ u16 ldsA[2][256 * 64];
  __shared__ u16 ldsB[2][256 * 64];
  f32x4 acc[8][4];
#pragma unroll
  for (int m = 0; m < 8; ++m)
#pragma unroll
    for (int n = 0; n < 4; ++n) acc[m][n] = f32x4{0.f, 0.f, 0.f, 0.f};

  const int bi = blockIdx.x, bj = blockIdx.y;   // 128 x 4
  const int r8 = tid >> 3;
  const int c_l = tid & 7;

  auto stage = [&](int buf, int kt) {
    const int k0 = kt * 64;
#pragma unroll
    for (int p = 0; p < 4; ++p) {
      const int row = p * 64 + r8;
      const int chunk = c_l ^ (row & 7);
      g2l16(Xn + (size_t)(bi * 256 + row) * D + k0 + chunk * 8,
            (u16*)((char*)&ldsA[buf][0] + p * 8192 + wid * 1024));
      g2l16(Wm + (size_t)(bj * 256 + row) * D + k0 + chunk * 8,
            (u16*)((char*)&ldsB[buf][0] + p * 8192 + wid * 1024));
    }
  };

  stage(0, 0);
  __syncthreads();
  int buf = 0;
  for (int kt = 0; kt < 16; ++kt) {
    if (kt < 15) stage(buf ^ 1, kt + 1);
#pragma unroll
    for (int ks = 0; ks < 2; ++ks) {
      const int kk = ks * 32 + (lane >> 4) * 8;
      short8 a[8], b[4];
#pragma unroll
      for (int m = 0; m < 8; ++m) {
        const int row = wr * 128 + m * 16 + (lane & 15);
        const int off = row * 128 + ((kk * 2) ^ ((row & 7) << 4));
        a[m] = *(const short8*)((const char*)&ldsA[buf][0] + off);
      }
#pragma unroll
      for (int n = 0; n < 4; ++n) {
        const int row = wc * 64 + n * 16 + (lane & 15);
        const int off = row * 128 + ((kk * 2) ^ ((row & 7) << 4));
        b[n] = *(const short8*)((const char*)&ldsB[buf][0] + off);
      }
      __builtin_amdgcn_s_setprio(1);
#pragma unroll
      for (int m = 0; m < 8; ++m)
#pragma unroll
        for (int n = 0; n < 4; ++n)
          acc[m][n] = __builtin_amdgcn_mfma_f32_16x16x32_bf16(
              a[m], b[n], acc[m][n], 0, 0, 0);
      __builtin_amdgcn_s_setprio(0);
    }
    __syncthreads();
    buf ^= 1;
  }
  const int or0 = bi * 256 + wr * 128, oc0 = bj * 256 + wc * 64;
#pragma unroll
  for (int m = 0; m < 8; ++m)
#pragma unroll
    for (int n = 0; n < 4; ++n) {
      const int col = oc0 + n * 16 + (lane & 15);
      const float bc = bias[col], gc = gate[col];
#pragma unroll
      for (int r = 0; r < 4; ++r) {
        const int row = or0 + m * 16 + (lane >> 4) * 4 + r;
        const float t = acc[m][n][r] + bc;
        out[(size_t)row * D + col] = t * t * gc;
      }
    }
}

// ---------------------------------------------------------------------------
extern "C" void kernel_launch(void* const* d_in, const int* in_sizes, int n_in,
                              void* d_out, int out_size, void* d_ws,
                              size_t ws_size, hipStream_t stream) {
  (void)in_sizes; (void)n_in; (void)out_size; (void)ws_size;
  const float* inp = (const float*)d_in[0];
  const float* Mr = (const float*)d_in[1];
  const float* Mi = (const float*)d_in[2];
  const float* bias = (const float*)d_in[3];
  const float* qg = (const float*)d_in[4];
  float* out = (float*)d_out;
  float* gate_out = out + (size_t)32768 * 1024;

  char* ws = (char*)d_ws;
  u16* Xn = (u16*)ws;  // 64 MB
  // per-matrix region (16 MB): 6 bf16 slots (2 MB) + q0 (4 MB f32).
  // lifetimes: s0 X->E3, s1 X2->Et->E3t, s2 X3->E1, s3 X4->E2,
  //            s4 q1t->E1t, s5 E2t
  auto slot = [&](int m, int s) -> u16* {
    return (u16*)(ws + 67108864 + (size_t)m * 16777216 + (size_t)s * 2097152);
  };
  auto q0p = [&](int m) -> float* {
    return (float*)(ws + 67108864 + (size_t)m * 16777216 + 12582912);
  };
  u16* W = (u16*)(ws + 100663296);          // 96 MB: 2 MB
  u32* bar = (u32*)(ws + 104857600);        // 100 MB: barrier state

  hipMemsetAsync(bar, 0, 256, stream);
  normalize_kernel<<<32768, 256, 0, stream>>>(inp, Xn);

  ChainParams cp{};
  cp.Mr = Mr; cp.Mi = Mi; cp.qg = qg; cp.gate_out = gate_out;
  cp.X0 = slot(0, 0); cp.X1 = slot(1, 0);
  for (int m = 0; m < 2; ++m) {
    cp.bqX[m] = slot(m, 0); cp.bqX2[m] = slot(m, 1);
    cp.bqX3[m] = slot(m, 2); cp.bqX4[m] = slot(m, 3);
    cp.bq_q0[m] = q0p(m); cp.bq_q1t[m] = slot(m, 4);
  }
  // r0 C1: X2 = -f(X,X) -> s1
  for (int m = 0; m < 2; ++m)
    cp.rounds[0][m] = CJob{slot(m, 0), slot(m, 0), nullptr, slot(m, 1),
                           nullptr, -1.f};
  cp.nunits[0] = 2;
  // r1 C2: X3 = -f(X2,X) -> s2 ; X4 = f(X2,X2) -> s3
  for (int m = 0; m < 2; ++m) {
    cp.rounds[1][m * 2 + 0] = CJob{slot(m, 1), slot(m, 0), nullptr, slot(m, 2),
                                   nullptr, -1.f};
    cp.rounds[1][m * 2 + 1] = CJob{slot(m, 1), slot(m, 1), nullptr, slot(m, 3),
                                   nullptr, 1.f};
  }
  cp.nunits[1] = 4;
  // [buildq + gate after r1]
  // r2 E = f(X4, q1t) + q0 -> s0, dual Et -> s1
  for (int m = 0; m < 2; ++m)
    cp.rounds[2][m] = CJob{slot(m, 3), slot(m, 4), q0p(m), slot(m, 0),
                           slot(m, 1), 1.f};
  cp.nunits[2] = 2;
  // r3 sq1: E1 = f(E,Et) -> s2, dual E1t -> s4
  for (int m = 0; m < 2; ++m)
    cp.rounds[3][m] = CJob{slot(m, 0), slot(m, 1), nullptr, slot(m, 2),
                           slot(m, 4), 1.f};
  cp.nunits[3] = 2;
  // r4 sq2: E2 = f(E1,E1t) -> s3, dual E2t -> s5
  for (int m = 0; m < 2; ++m)
    cp.rounds[4][m] = CJob{slot(m, 2), slot(m, 4), nullptr, slot(m, 3),
                           slot(m, 5), 1.f};
  cp.nunits[4] = 2;
  // r5 sq3: E3 = f(E2,E2t) -> s0, dual E3t -> s1
  for (int m = 0; m < 2; ++m)
    cp.rounds[5][m] = CJob{slot(m, 3), slot(m, 5), nullptr, slot(m, 0),
                           slot(m, 1), 1.f};
  cp.nunits[5] = 2;
  // r6 W = U^T = f(E3t_B, E3_A)
  cp.rounds[6][0] = CJob{slot(1, 1), slot(0, 0), nullptr, W, nullptr, 1.f};
  cp.nunits[6] = 1;
  cp.bar_cnt = bar;
  cp.bar_gen = bar + 32;  // separate 128B line

  chain_fused<<<512, 256, 0, stream>>>(cp);

  main_gemm_kernel<<<dim3(128, 4), 512, 0, stream>>>(Xn, W, bias, gate_out,
                                                     out);
}

// Round 7
// 603.298 us; speedup vs baseline: 1.0789x; 1.0789x over previous
//
#include <hip/hip_runtime.h>

// ---------------------------------------------------------------------------
// RefinedQuantumEntanglementLayer on MI355X (gfx950)
//
// out = (l2norm(x) @ expm(Mr-Mr^T) @ expm(Mi-Mi^T) + bias)^2 * softmax(qg)
//
// r7: same fused persistent chain as r6, with the grid-barrier spin FIXED.
// r6's spin polled `gen` with an ACQUIRE agent load per iteration; on
// gfx950 each such acquire emits buffer_inv (whole-L2 invalidate, per-XCD
// non-coherent L2) -> 512 spinners continuously wiped L2 chip-wide
// (measured: FETCH 134MB, 383GB/s, MfmaUtil 2.4%, 533us). Now: RELAXED
// polls (agent atomics bypass L2 per-line, no invalidate) + ONE acquire
// fence after the spin exits -- the same one-time cost a kernel boundary
// pays.
//
// Chain math (deg-8 Paterson-Stockmeyer, s=3, verified r6 absmax 4.2e-7):
//   X2 = -f(X,X); X3 = -f(X2,X); X4 = f(X2,X2)        [f(A,B) = A*B^T]
//   q0 = I+X+X2/2+X3/6 (f32); q1t = elementwise-transposed q1 (odd flips)
//   E  = f(X4,q1t)+q0 [dual-write -> Et]
//   squarings E' = f(E,Et) [dual -> E't]; W = U^T = f(E3t_B, E3_A)
// main: out = f(Xn,W), epilogue (.+bias)^2*gate (r5 256^2 kernel).
// ---------------------------------------------------------------------------

typedef unsigned int u32;
typedef unsigned short u16;
typedef __attribute__((ext_vector_type(8))) short short8;   // 8 x bf16 raw
typedef __attribute__((ext_vector_type(4))) float f32x4;

#define GLOBAL_AS __attribute__((address_space(1)))
#define LDS_AS    __attribute__((address_space(3)))

constexpr int D = 1024;
constexpr float EXPM_SCALE = 1.0f / 8.0f;   // s = 3 squarings

__device__ __forceinline__ u16 f2bf(float f) {
  union { float f; u32 u; } v; v.f = f;
  u32 r = (v.u + 0x7FFFu + ((v.u >> 16) & 1u)) >> 16;
  return (u16)r;
}
__device__ __forceinline__ float bf2f(u16 u) {
  union { u32 u; float f; } v; v.u = ((u32)u) << 16;
  return v.f;
}

// async global->LDS, 16B per lane; lds base must be wave-uniform.
__device__ __forceinline__ void g2l16(const void* g, void* l) {
  __builtin_amdgcn_global_load_lds((const GLOBAL_AS u32*)g, (LDS_AS u32*)l,
                                   16, 0, 0);
}

// ---------------------------------------------------------------------------
// normalize rows of x -> bf16
__global__ __launch_bounds__(256) void normalize_kernel(
    const float* __restrict__ x, u16* __restrict__ Xn) {
  const int r = blockIdx.x;
  const int t = threadIdx.x;
  const float4 v = ((const float4*)(x + (size_t)r * D))[t];
  float ss = v.x * v.x + v.y * v.y + v.z * v.z + v.w * v.w;
  for (int o = 32; o; o >>= 1) ss += __shfl_down(ss, o);
  __shared__ float s4[4];
  if ((t & 63) == 0) s4[t >> 6] = ss;
  __syncthreads();
  const float tot = s4[0] + s4[1] + s4[2] + s4[3];
  const float inv = rsqrtf(fmaxf(tot, 1e-12f));
  ushort4 o4;
  o4.x = f2bf(v.x * inv); o4.y = f2bf(v.y * inv);
  o4.z = f2bf(v.z * inv); o4.w = f2bf(v.w * inv);
  ((ushort4*)(Xn + (size_t)r * D))[t] = o4;
}

// ---------------------------------------------------------------------------
// fused chain kernel
struct CJob {
  const u16 *A, *B;
  const float* C;
  u16 *Dst, *DT;
  float alpha;
};
struct ChainParams {
  const float *Mr, *Mi, *qg;
  float* gate_out;
  u16 *X0, *X1;
  const u16 *bqX[2], *bqX2[2], *bqX3[2], *bqX4[2];
  float* bq_q0[2];
  u16* bq_q1t[2];
  CJob rounds[7][4];
  int nunits[7];
  u32 *bar_cnt, *bar_gen;
};

// grid barrier. Release: ACQ_REL fetch_add (emits L2 writeback covering the
// whole block's writes -- workgroup-happens-before via __syncthreads).
// Spin: RELAXED agent loads (per-line L2 bypass, NO buffer_inv per poll --
// r6's in-loop ACQUIRE was the 5x regression). Acquire: one __threadfence
// per block after exit. Spin capped (~0.7s) so failure is loud, not a hang.
__device__ __forceinline__ void gsync(u32* cnt, u32* gen, u32 nb) {
  __syncthreads();
  if (threadIdx.x == 0) {
    const u32 g =
        __hip_atomic_load(gen, __ATOMIC_RELAXED, __HIP_MEMORY_SCOPE_AGENT);
    const u32 a = __hip_atomic_fetch_add(cnt, 1u, __ATOMIC_ACQ_REL,
                                         __HIP_MEMORY_SCOPE_AGENT);
    if (a == nb - 1u) {
      __hip_atomic_store(cnt, 0u, __ATOMIC_RELAXED, __HIP_MEMORY_SCOPE_AGENT);
      __hip_atomic_store(gen, g + 1u, __ATOMIC_RELEASE,
                         __HIP_MEMORY_SCOPE_AGENT);
    } else {
      for (u32 it = 0; it < 3000000u; ++it) {
        if (__hip_atomic_load(gen, __ATOMIC_RELAXED,
                              __HIP_MEMORY_SCOPE_AGENT) != g)
          break;
        __builtin_amdgcn_s_sleep(8);
      }
    }
  }
  __syncthreads();
  __threadfence();  // one-time acquire/inv per block; covers all threads
}

// X = (M - M^T) * EXPM_SCALE -> bf16 (one 64x64 tile)
__device__ void skew_tile(const float* M, u16* X, int bi, int bj, int tid,
                          char* smem) {
  float(*t2)[67] = (float(*)[67])smem;
  const int r0 = tid >> 4, c0 = (tid & 15) * 4;
  float4 own[4];
#pragma unroll
  for (int i = 0; i < 4; ++i) {
    const int r = i * 16 + r0;
    own[i] = *(const float4*)(M + (size_t)(bi * 64 + r) * D + bj * 64 + c0);
    const float4 tr =
        *(const float4*)(M + (size_t)(bj * 64 + r) * D + bi * 64 + c0);
    t2[r][c0 + 0] = tr.x; t2[r][c0 + 1] = tr.y;
    t2[r][c0 + 2] = tr.z; t2[r][c0 + 3] = tr.w;
  }
  __syncthreads();
#pragma unroll
  for (int i = 0; i < 4; ++i) {
    const int r = i * 16 + r0;
    const float o[4] = {own[i].x, own[i].y, own[i].z, own[i].w};
    ushort4 hv;
    u16* hp = (u16*)&hv;
#pragma unroll
    for (int j = 0; j < 4; ++j)
      hp[j] = f2bf((o[j] - t2[c0 + j][r]) * EXPM_SCALE);
    *(ushort4*)(X + (size_t)(bi * 64 + r) * D + bj * 64 + c0) = hv;
  }
}

// one 64x64 GEMM tile: Dst = alpha*(A*B^T) [+C], optional dual write DT.
// r3-proven body: BK=64, 4 waves (2x2, 32x32), dbuf 1-ahead prefetch.
__device__ void gemm_tile(const CJob jb, int bi, int bj, int tid, u16* ldsA,
                          u16* ldsB) {
  const int w = tid >> 6, lane = tid & 63;
  const int wr = w >> 1, wc = w & 1;
  f32x4 acc[2][2];
#pragma unroll
  for (int m = 0; m < 2; ++m)
#pragma unroll
    for (int n = 0; n < 2; ++n) acc[m][n] = f32x4{0.f, 0.f, 0.f, 0.f};
  const int r_l = lane >> 3, c_l = lane & 7;

  auto stage = [&](int buf, int kt) {
    const int k0 = kt * 64;
#pragma unroll
    for (int p = 0; p < 2; ++p) {
      const int row = p * 32 + w * 8 + r_l;
      const int chunk = c_l ^ (row & 7);  // inverse swizzle on global source
      g2l16(jb.A + (size_t)(bi * 64 + row) * D + k0 + chunk * 8,
            (char*)ldsA + buf * 8192 + p * 4096 + w * 1024);
      g2l16(jb.B + (size_t)(bj * 64 + row) * D + k0 + chunk * 8,
            (char*)ldsB + buf * 8192 + p * 4096 + w * 1024);
    }
  };

  stage(0, 0);
  __syncthreads();
  int buf = 0;
  for (int kt = 0; kt < 16; ++kt) {
    if (kt < 15) stage(buf ^ 1, kt + 1);  // prefetch flies under MFMAs
#pragma unroll
    for (int h = 0; h < 2; ++h) {
      const int kk = h * 32 + (lane >> 4) * 8;
      short8 a[2], b[2];
#pragma unroll
      for (int m = 0; m < 2; ++m) {
        const int row = wr * 32 + m * 16 + (lane & 15);
        const int off = row * 128 + ((kk * 2) ^ ((row & 7) << 4));
        a[m] = *(const short8*)((const char*)ldsA + buf * 8192 + off);
      }
#pragma unroll
      for (int n = 0; n < 2; ++n) {
        const int row = wc * 32 + n * 16 + (lane & 15);
        const int off = row * 128 + ((kk * 2) ^ ((row & 7) << 4));
        b[n] = *(const short8*)((const char*)ldsB + buf * 8192 + off);
      }
#pragma unroll
      for (int m = 0; m < 2; ++m)
#pragma unroll
        for (int n = 0; n < 2; ++n)
          acc[m][n] = __builtin_amdgcn_mfma_f32_16x16x32_bf16(
              a[m], b[n], acc[m][n], 0, 0, 0);
    }
    __syncthreads();
    buf ^= 1;
  }
  const int or0 = bi * 64 + wr * 32, oc0 = bj * 64 + wc * 32;
#pragma unroll
  for (int m = 0; m < 2; ++m)
#pragma unroll
    for (int n = 0; n < 2; ++n) {
      const int row0 = or0 + m * 16 + (lane >> 4) * 4;
      const int col = oc0 + n * 16 + (lane & 15);
      ushort4 dv;
      u16* dp = (u16*)&dv;
#pragma unroll
      for (int r = 0; r < 4; ++r) {
        float v = acc[m][n][r] * jb.alpha;
        if (jb.C) v += jb.C[(size_t)(row0 + r) * D + col];
        dp[r] = f2bf(v);
        jb.Dst[(size_t)(row0 + r) * D + col] = dp[r];
      }
      if (jb.DT)  // transposed tile: DT[col][row0..row0+3], one 8B store
        *(ushort4*)(jb.DT + (size_t)col * D + row0) = dv;
    }
}

// elementwise: q0 = I+X+X2/2+X3/6 (f32); q1t = I/24 - X/120 + X2/720
//              - X3/5040 + X4/40320 (bf16)   [8 elems/thread/matrix]
__device__ void buildq_body(const ChainParams& p, int bid, int tid) {
  const int gtid = bid * 256 + tid;
  const size_t idx0 = (size_t)gtid * 8;
  const int i = (int)(idx0 >> 10), j0 = (int)(idx0 & 1023);
#pragma unroll
  for (int m = 0; m < 2; ++m) {
    const short8 xv = *(const short8*)(p.bqX[m] + idx0);
    const short8 x2v = *(const short8*)(p.bqX2[m] + idx0);
    const short8 x3v = *(const short8*)(p.bqX3[m] + idx0);
    const short8 x4v = *(const short8*)(p.bqX4[m] + idx0);
    float q0o[8];
    short8 q1o;
#pragma unroll
    for (int k = 0; k < 8; ++k) {
      const float d = (i == (j0 + k)) ? 1.f : 0.f;
      const float x = bf2f((u16)xv[k]);
      const float x2 = bf2f((u16)x2v[k]);
      const float x3 = bf2f((u16)x3v[k]);
      const float x4 = bf2f((u16)x4v[k]);
      q0o[k] = d + x + x2 * 0.5f + x3 * (1.f / 6.f);
      q1o[k] = (short)f2bf(d * (1.f / 24.f) - x * (1.f / 120.f) +
                           x2 * (1.f / 720.f) - x3 * (1.f / 5040.f) +
                           x4 * (1.f / 40320.f));
    }
#pragma unroll
    for (int k = 0; k < 8; ++k) p.bq_q0[m][idx0 + k] = q0o[k];
    *(short8*)(p.bq_q1t[m] + idx0) = q1o;
  }
}

// softmax of qg (block 0 only, 256 threads x 4 elems)
__device__ void gate_body(const float* qg, float* gout, int tid, char* smem) {
  float* red = (float*)smem;
  const float4 v = ((const float4*)qg)[tid];
  float mx = fmaxf(fmaxf(v.x, v.y), fmaxf(v.z, v.w));
#pragma unroll
  for (int o = 32; o; o >>= 1) mx = fmaxf(mx, __shfl_xor(mx, o));
  if ((tid & 63) == 0) red[tid >> 6] = mx;
  __syncthreads();
  const float M = fmaxf(fmaxf(red[0], red[1]), fmaxf(red[2], red[3]));
  __syncthreads();
  const float e0 = __expf(v.x - M), e1 = __expf(v.y - M),
              e2 = __expf(v.z - M), e3 = __expf(v.w - M);
  float s = e0 + e1 + e2 + e3;
#pragma unroll
  for (int o = 32; o; o >>= 1) s += __shfl_xor(s, o);
  if ((tid & 63) == 0) red[tid >> 6] = s;
  __syncthreads();
  const float S = red[0] + red[1] + red[2] + red[3];
  const float4 o4 = {e0 / S, e1 / S, e2 / S, e3 / S};
  ((float4*)gout)[tid] = o4;
}

__global__ __launch_bounds__(256, 2) void chain_fused(ChainParams p) {
  __shared__ __align__(16) char smem[32768];
  u16* ldsA = (u16*)smem;            // [2][4096] u16
  u16* ldsB = (u16*)(smem + 16384);  // [2][4096] u16
  const int bid = blockIdx.x, tid = threadIdx.x;
  const u32 nb = gridDim.x;

  // P0: skew (512 jobs: mat x 16 x 16)
  {
    const int z = bid >> 8, t = bid & 255;
    skew_tile(z ? p.Mi : p.Mr, z ? p.X1 : p.X0, t >> 4, t & 15, tid, smem);
  }
  gsync(p.bar_cnt, p.bar_gen, nb);

  // 7 GEMM rounds; buildq(+gate) interleaved after round 1
  for (int r = 0; r < 7; ++r) {
    const int njobs = p.nunits[r] << 8;
    for (int j = bid; j < njobs; j += 512) {
      gemm_tile(p.rounds[r][j >> 8], (j >> 4) & 15, j & 15, tid, ldsA, ldsB);
    }
    if (r < 6) gsync(p.bar_cnt, p.bar_gen, nb);
    if (r == 1) {
      buildq_body(p, bid, tid);
      if (bid == 0) gate_body(p.qg, p.gate_out, tid, smem);
      gsync(p.bar_cnt, p.bar_gen, nb);
    }
  }
}

// ---------------------------------------------------------------------------
// main GEMM (r5, unchanged): out[r][c] = (f(Xn,W) + bias[c])^2 * gate[c]
// 256x256 tile, BK=64, 8 waves (2x4), 128 KiB dbuf LDS, 1-ahead prefetch.
__global__ __launch_bounds__(512, 1) void main_gemm_kernel(
    const u16* __restrict__ Xn, const u16* __restrict__ Wm,
    const float* __restrict__ bias, const float* __restrict__ gate,
    float* __restrict__ out) {
  const int tid = threadIdx.x;
  const int wid = tid >> 6, lane = tid & 63;
  const int wr = wid >> 2, wc = wid & 3;   // 2 x 4 waves
  __shared__ u16 ldsA[2][256 * 64];
  __shared__ u16 ldsB[2][256 * 64];
  f32x4 acc[8][4];
#pragma unroll
  for (int m = 0; m < 8; ++m)
#pragma unroll
    for (int n = 0; n < 4; ++n) acc[m][n] = f32x4{0.f, 0.f, 0.f, 0.f};

  const int bi = blockIdx.x, bj = blockIdx.y;   // 128 x 4
  const int r8 = tid >> 3;
  const int c_l = tid & 7;

  auto stage = [&](int buf, int kt) {
    const int k0 = kt * 64;
#pragma unroll
    for (int p = 0; p < 4; ++p) {
      const int row = p * 64 + r8;
      const int chunk = c_l ^ (row & 7);
      g2l16(Xn + (size_t)(bi * 256 + row) * D + k0 + chunk * 8,
            (u16*)((char*)&ldsA[buf][0] + p * 8192 + wid * 1024));
      g2l16(Wm + (size_t)(bj * 256 + row) * D + k0 + chunk * 8,
            (u16*)((char*)&ldsB[buf][0] + p * 8192 + wid * 1024));
    }
  };

  stage(0, 0);
  __syncthreads();
  int buf = 0;
  for (int kt = 0; kt < 16; ++kt) {
    if (kt < 15) stage(buf ^ 1, kt + 1);
#pragma unroll
    for (int ks = 0; ks < 2; ++ks) {
      const int kk = ks * 32 + (lane >> 4) * 8;
      short8 a[8], b[4];
#pragma unroll
      for (int m = 0; m < 8; ++m) {
        const int row = wr * 128 + m * 16 + (lane & 15);
        const int off = row * 128 + ((kk * 2) ^ ((row & 7) << 4));
        a[m] = *(const short8*)((const char*)&ldsA[buf][0] + off);
      }
#pragma unroll
      for (int n = 0; n < 4; ++n) {
        const int row = wc * 64 + n * 16 + (lane & 15);
        const int off = row * 128 + ((kk * 2) ^ ((row & 7) << 4));
        b[n] = *(const short8*)((const char*)&ldsB[buf][0] + off);
      }
      __builtin_amdgcn_s_setprio(1);
#pragma unroll
      for (int m = 0; m < 8; ++m)
#pragma unroll
        for (int n = 0; n < 4; ++n)
          acc[m][n] = __builtin_amdgcn_mfma_f32_16x16x32_bf16(
              a[m], b[n], acc[m][n], 0, 0, 0);
      __builtin_amdgcn_s_setprio(0);
    }
    __syncthreads();
    buf ^= 1;
  }
  const int or0 = bi * 256 + wr * 128, oc0 = bj * 256 + wc * 64;
#pragma unroll
  for (int m = 0; m < 8; ++m)
#pragma unroll
    for (int n = 0; n < 4; ++n) {
      const int col = oc0 + n * 16 + (lane & 15);
      const float bc = bias[col], gc = gate[col];
#pragma unroll
      for (int r = 0; r < 4; ++r) {
        const int row = or0 + m * 16 + (lane >> 4) * 4 + r;
        const float t = acc[m][n][r] + bc;
        out[(size_t)row * D + col] = t * t * gc;
      }
    }
}

// ---------------------------------------------------------------------------
extern "C" void kernel_launch(void* const* d_in, const int* in_sizes, int n_in,
                              void* d_out, int out_size, void* d_ws,
                              size_t ws_size, hipStream_t stream) {
  (void)in_sizes; (void)n_in; (void)out_size; (void)ws_size;
  const float* inp = (const float*)d_in[0];
  const float* Mr = (const float*)d_in[1];
  const float* Mi = (const float*)d_in[2];
  const float* bias = (const float*)d_in[3];
  const float* qg = (const float*)d_in[4];
  float* out = (float*)d_out;
  float* gate_out = out + (size_t)32768 * 1024;

  char* ws = (char*)d_ws;
  u16* Xn = (u16*)ws;  // 64 MB
  // per-matrix region (16 MB): 6 bf16 slots (2 MB) + q0 (4 MB f32).
  // lifetimes: s0 X->E3, s1 X2->Et->E3t, s2 X3->E1, s3 X4->E2,
  //            s4 q1t->E1t, s5 E2t
  auto slot = [&](int m, int s) -> u16* {
    return (u16*)(ws + 67108864 + (size_t)m * 16777216 + (size_t)s * 2097152);
  };
  auto q0p = [&](int m) -> float* {
    return (float*)(ws + 67108864 + (size_t)m * 16777216 + 12582912);
  };
  u16* W = (u16*)(ws + 100663296);          // 96 MB: 2 MB
  u32* bar = (u32*)(ws + 104857600);        // 100 MB: barrier state

  hipMemsetAsync(bar, 0, 256, stream);
  normalize_kernel<<<32768, 256, 0, stream>>>(inp, Xn);

  ChainParams cp{};
  cp.Mr = Mr; cp.Mi = Mi; cp.qg = qg; cp.gate_out = gate_out;
  cp.X0 = slot(0, 0); cp.X1 = slot(1, 0);
  for (int m = 0; m < 2; ++m) {
    cp.bqX[m] = slot(m, 0); cp.bqX2[m] = slot(m, 1);
    cp.bqX3[m] = slot(m, 2); cp.bqX4[m] = slot(m, 3);
    cp.bq_q0[m] = q0p(m); cp.bq_q1t[m] = slot(m, 4);
  }
  // r0 C1: X2 = -f(X,X) -> s1
  for (int m = 0; m < 2; ++m)
    cp.rounds[0][m] = CJob{slot(m, 0), slot(m, 0), nullptr, slot(m, 1),
                           nullptr, -1.f};
  cp.nunits[0] = 2;
  // r1 C2: X3 = -f(X2,X) -> s2 ; X4 = f(X2,X2) -> s3
  for (int m = 0; m < 2; ++m) {
    cp.rounds[1][m * 2 + 0] = CJob{slot(m, 1), slot(m, 0), nullptr, slot(m, 2),
                                   nullptr, -1.f};
    cp.rounds[1][m * 2 + 1] = CJob{slot(m, 1), slot(m, 1), nullptr, slot(m, 3),
                                   nullptr, 1.f};
  }
  cp.nunits[1] = 4;
  // [buildq + gate after r1]
  // r2 E = f(X4, q1t) + q0 -> s0, dual Et -> s1
  for (int m = 0; m < 2; ++m)
    cp.rounds[2][m] = CJob{slot(m, 3), slot(m, 4), q0p(m), slot(m, 0),
                           slot(m, 1), 1.f};
  cp.nunits[2] = 2;
  // r3 sq1: E1 = f(E,Et) -> s2, dual E1t -> s4
  for (int m = 0; m < 2; ++m)
    cp.rounds[3][m] = CJob{slot(m, 0), slot(m, 1), nullptr, slot(m, 2),
                           slot(m, 4), 1.f};
  cp.nunits[3] = 2;
  // r4 sq2: E2 = f(E1,E1t) -> s3, dual E2t -> s5
  for (int m = 0; m < 2; ++m)
    cp.rounds[4][m] = CJob{slot(m, 2), slot(m, 4), nullptr, slot(m, 3),
                           slot(m, 5), 1.f};
  cp.nunits[4] = 2;
  // r5 sq3: E3 = f(E2,E2t) -> s0, dual E3t -> s1
  for (int m = 0; m < 2; ++m)
    cp.rounds[5][m] = CJob{slot(m, 3), slot(m, 5), nullptr, slot(m, 0),
                           slot(m, 1), 1.f};
  cp.nunits[5] = 2;
  // r6 W = U^T = f(E3t_B, E3_A)
  cp.rounds[6][0] = CJob{slot(1, 1), slot(0, 0), nullptr, W, nullptr, 1.f};
  cp.nunits[6] = 1;
  cp.bar_cnt = bar;
  cp.bar_gen = bar + 32;  // separate 128B line

  chain_fused<<<512, 256, 0, stream>>>(cp);

  main_gemm_kernel<<<dim3(128, 4), 512, 0, stream>>>(Xn, W, bias, gate_out,
                                                     out);
}